// Round 4
// baseline (1125.509 us; speedup 1.0000x reference)
//
#include <hip/hip_runtime.h>

// OnsetLSTM: 2-layer LSTM, B=256, T=512, D=160, H=128, fp32 in/out.
// 256 blocks (1 batch row each) x 1024 threads (16 waves, 4/SIMD).
// Thread = (col c=tid>>3, gate-pair tp=(tid>>2)&1 [0:i,f 1:g,o], K-chunk s=tid&3).
// Each thread: 2 gate rows x K/4 as 80 f16-pair VGPRs (fits under the 128-reg
// ceiling the compiler enforces -> no spills, unlike R2's 144/thread).
// Reduce over s: 2x quad_perm DPP (VALU). Exchange activated gate pairs
// across tp: 2x ds_swizzle xor-4. Cell replicated per 8-lane group.
// 1 barrier/step. Layer-0 h-sequence lives in LDS (128KB) and doubles as the
// recurrent h source for layer 0 (h1s[t-1]) and layer-1 input.

typedef _Float16 half2_t __attribute__((ext_vector_type(2)));

#define TSTEPS 512
#define HID 128

static __device__ __forceinline__ unsigned pack2(float a, float b) {
  half2_t h; h[0] = (_Float16)a; h[1] = (_Float16)b;
  return __builtin_bit_cast(unsigned, h);
}

static __device__ __forceinline__ float dot2f(unsigned a, unsigned b, float c) {
#if __has_builtin(__builtin_amdgcn_fdot2)
  return __builtin_amdgcn_fdot2(__builtin_bit_cast(half2_t, a),
                                __builtin_bit_cast(half2_t, b), c, false);
#else
  half2_t x = __builtin_bit_cast(half2_t, a);
  half2_t y = __builtin_bit_cast(half2_t, b);
  float r = c;
  r = fmaf((float)x[0], (float)y[0], r);
  r = fmaf((float)x[1], (float)y[1], r);
  return r;
#endif
}

static __device__ __forceinline__ float fast_rcp(float x) {
#if __has_builtin(__builtin_amdgcn_rcpf)
  return __builtin_amdgcn_rcpf(x);
#else
  return 1.0f / x;
#endif
}
static __device__ __forceinline__ float fast_exp2(float x) {
#if __has_builtin(__builtin_amdgcn_exp2f)
  return __builtin_amdgcn_exp2f(x);
#else
  return exp2f(x);
#endif
}
// sigm(x) = 1/(1+2^(-x*log2e)); saturates correctly at +-inf
static __device__ __forceinline__ float sigm(float x) {
  return fast_rcp(1.0f + fast_exp2(x * -1.44269504f));
}
static __device__ __forceinline__ float tanh_f(float x) {
  // 1 - 2/(exp2(2x*log2e)+1); saturates correctly both ways
  float e = fast_exp2(x * 2.885390082f);
  return 1.0f - 2.0f * fast_rcp(e + 1.0f);
}

// butterfly add over quad (aligned groups of 4): CTRL 0xB1=xor1, 0x4E=xor2
template <int CTRL>
static __device__ __forceinline__ float qp_add(float v) {
  int iv = __builtin_bit_cast(int, v);
  int t = __builtin_amdgcn_update_dpp(iv, iv, CTRL, 0xF, 0xF, true);
  return v + __builtin_bit_cast(float, t);
}
// lane ^ 4 exchange (ds_swizzle BitMode: xor=4, and=0x1F)
static __device__ __forceinline__ float swz_xor4(float v) {
  int t = __builtin_amdgcn_ds_swizzle(__builtin_bit_cast(int, v), 0x101F);
  return __builtin_bit_cast(float, t);
}

__global__ __launch_bounds__(1024, 1) void lstm_fused(
    const float* __restrict__ x,     // [256,512,160]
    const float* __restrict__ h0,    // [2,256,128]
    const float* __restrict__ c0,    // [2,256,128]
    const float* __restrict__ Wih0,  // [512,160]
    const float* __restrict__ Whh0,  // [512,128]
    const float* __restrict__ bih0, const float* __restrict__ bhh0,
    const float* __restrict__ Wih1,  // [512,128]
    const float* __restrict__ Whh1,  // [512,128]
    const float* __restrict__ bih1, const float* __restrict__ bhh1,
    float* __restrict__ out)         // [256,128]
{
  const int b  = blockIdx.x;
  const int tid = threadIdx.x;
  const int c  = tid >> 3;         // cell column 0..127
  const int tp = (tid >> 2) & 1;   // 0 -> rows {i,f}; 1 -> rows {g,o}
  const int s  = tid & 3;          // K-chunk 0..3

  __shared__ unsigned h1s[TSTEPS][64];  // 128 KB: layer-0 h_t as f16 pairs
  __shared__ unsigned xbuf[2][96];      // x_t f16 pairs, padded 80->96, dbuf
  __shared__ unsigned h0buf[64];        // layer-0 initial h
  __shared__ unsigned hbuf[2][64];      // layer-1 recurrent h, dbuf

  // ======================= Phase 0: layer 0 =======================
  {
    // weight registers: rows r = (2*tp+u)*128 + c, K split into 4 chunks.
    // x-part padded: pairs 0..79 real (160 floats), 80..95 zero.
    unsigned wx[2][24], wh[2][16];
    float bias[2];
#pragma unroll
    for (int u = 0; u < 2; ++u) {
      const int r = (tp * 2 + u) * HID + c;
#pragma unroll
      for (int j = 0; j < 24; ++j) {
        int p = 24 * s + j;
        float a0 = (2 * p < 160) ? Wih0[r * 160 + 2 * p] : 0.f;
        float a1 = (2 * p + 1 < 160) ? Wih0[r * 160 + 2 * p + 1] : 0.f;
        wx[u][j] = pack2(a0, a1);
      }
#pragma unroll
      for (int j = 0; j < 16; ++j) {
        int p = 16 * s + j;
        wh[u][j] = pack2(Whh0[r * HID + 2 * p], Whh0[r * HID + 2 * p + 1]);
      }
      bias[u] = bih0[r] + bhh0[r];
    }

    float cst = c0[b * HID + c];  // replicated across the 8-lane group

    if (tid < 64) h0buf[tid] = pack2(h0[b * HID + 2 * tid], h0[b * HID + 2 * tid + 1]);
    if (tid < 80) {
      float2 v = *(const float2*)&x[((size_t)b * TSTEPS + 0) * 160 + 2 * tid];
      xbuf[0][tid] = pack2(v.x, v.y);
    }
    if (tid >= 80 && tid < 96) { xbuf[0][tid] = 0u; xbuf[1][tid] = 0u; }
    float2 xA = make_float2(0.f, 0.f);  // x_{t+1} in regs
    if (tid < 80) xA = *(const float2*)&x[((size_t)b * TSTEPS + 1) * 160 + 2 * tid];
    __syncthreads();

#pragma unroll 1
    for (int t = 0; t < TSTEPS; ++t) {
      // issue x_{t+2} load now; lands before it is written next iteration
      float2 xB = xA;
      if (tid < 80) {
        int tn = (t + 2 < TSTEPS) ? t + 2 : TSTEPS - 1;
        xB = *(const float2*)&x[((size_t)b * TSTEPS + tn) * 160 + 2 * tid];
      }

      const uint4* xs = (const uint4*)&xbuf[t & 1][24 * s];
      const uint4* hs = (t == 0) ? (const uint4*)&h0buf[16 * s]
                                 : (const uint4*)&h1s[t - 1][16 * s];
      float a0 = 0.f, a1 = 0.f, b0 = 0.f, b1 = 0.f;
#pragma unroll
      for (int k = 0; k < 6; ++k) {
        uint4 v = xs[k];
        a0 = dot2f(v.x, wx[0][4 * k + 0], a0);
        a0 = dot2f(v.y, wx[0][4 * k + 1], a0);
        a1 = dot2f(v.z, wx[0][4 * k + 2], a1);
        a1 = dot2f(v.w, wx[0][4 * k + 3], a1);
        b0 = dot2f(v.x, wx[1][4 * k + 0], b0);
        b0 = dot2f(v.y, wx[1][4 * k + 1], b0);
        b1 = dot2f(v.z, wx[1][4 * k + 2], b1);
        b1 = dot2f(v.w, wx[1][4 * k + 3], b1);
      }
#pragma unroll
      for (int k = 0; k < 4; ++k) {
        uint4 v = hs[k];
        a0 = dot2f(v.x, wh[0][4 * k + 0], a0);
        a0 = dot2f(v.y, wh[0][4 * k + 1], a0);
        a1 = dot2f(v.z, wh[0][4 * k + 2], a1);
        a1 = dot2f(v.w, wh[0][4 * k + 3], a1);
        b0 = dot2f(v.x, wh[1][4 * k + 0], b0);
        b0 = dot2f(v.y, wh[1][4 * k + 1], b0);
        b1 = dot2f(v.z, wh[1][4 * k + 2], b1);
        b1 = dot2f(v.w, wh[1][4 * k + 3], b1);
      }
      float accA = a0 + a1, accB = b0 + b1;
      // butterfly over s (quad): all 4 lanes end with the full K-sum
      accA = qp_add<0xB1>(accA); accA = qp_add<0x4E>(accA);
      accB = qp_add<0xB1>(accB); accB = qp_add<0x4E>(accB);
      float g0 = accA + bias[0];  // tp0: i-gate ; tp1: g-gate
      float g1 = accB + bias[1];  // tp0: f-gate ; tp1: o-gate
      // tp1 applies tanh to g0 via tanh(x)=2*sigm(2x)-1 (one exp+rcp either way)
      float m = tp ? 2.0f : 1.0f;
      float act0 = m * sigm(m * g0) - (tp ? 1.0f : 0.0f);  // tp0: î ; tp1: ĝ
      float act1 = sigm(g1);                               // tp0: f̂ ; tp1: ô
      // exchange across the two quads of the 8-lane group
      float e0 = swz_xor4(act0);
      float e1 = swz_xor4(act1);
      float ih = tp ? e0 : act0;
      float fh = tp ? e1 : act1;
      float gh = tp ? act0 : e0;
      float oh = tp ? act1 : e1;
      cst = fh * cst + ih * gh;
      float h = oh * tanh_f(cst);

      if ((tid & 7) == 0)
        ((_Float16*)h1s)[t * HID + c] = (_Float16)h;  // recurrent + layer-1 input
      if (tid < 80) xbuf[(t + 1) & 1][tid] = pack2(xA.x, xA.y);
      __syncthreads();
      xA = xB;
    }
  }

  // ======================= Phase 1: layer 1 =======================
  {
    unsigned w1x[2][16], w1h[2][16];
    float bias[2];
#pragma unroll
    for (int u = 0; u < 2; ++u) {
      const int r = (tp * 2 + u) * HID + c;
#pragma unroll
      for (int j = 0; j < 16; ++j) {
        int p = 16 * s + j;
        w1x[u][j] = pack2(Wih1[r * HID + 2 * p], Wih1[r * HID + 2 * p + 1]);
        w1h[u][j] = pack2(Whh1[r * HID + 2 * p], Whh1[r * HID + 2 * p + 1]);
      }
      bias[u] = bih1[r] + bhh1[r];
    }

    const float* h0b = h0 + 256 * HID;
    const float* c0b = c0 + 256 * HID;
    float cst = c0b[b * HID + c];
    if (tid < 64) hbuf[0][tid] = pack2(h0b[b * HID + 2 * tid], h0b[b * HID + 2 * tid + 1]);
    __syncthreads();

    float hlast = 0.f;
#pragma unroll 1
    for (int t = 0; t < TSTEPS; ++t) {
      const uint4* xs = (const uint4*)&h1s[t][16 * s];      // layer-0 h_t
      const uint4* hs = (const uint4*)&hbuf[t & 1][16 * s]; // own h_{t-1}
      float a0 = 0.f, a1 = 0.f, b0 = 0.f, b1 = 0.f;
#pragma unroll
      for (int k = 0; k < 4; ++k) {
        uint4 v = xs[k];
        a0 = dot2f(v.x, w1x[0][4 * k + 0], a0);
        a0 = dot2f(v.y, w1x[0][4 * k + 1], a0);
        a1 = dot2f(v.z, w1x[0][4 * k + 2], a1);
        a1 = dot2f(v.w, w1x[0][4 * k + 3], a1);
        b0 = dot2f(v.x, w1x[1][4 * k + 0], b0);
        b0 = dot2f(v.y, w1x[1][4 * k + 1], b0);
        b1 = dot2f(v.z, w1x[1][4 * k + 2], b1);
        b1 = dot2f(v.w, w1x[1][4 * k + 3], b1);
      }
#pragma unroll
      for (int k = 0; k < 4; ++k) {
        uint4 v = hs[k];
        a0 = dot2f(v.x, w1h[0][4 * k + 0], a0);
        a0 = dot2f(v.y, w1h[0][4 * k + 1], a0);
        a1 = dot2f(v.z, w1h[0][4 * k + 2], a1);
        a1 = dot2f(v.w, w1h[0][4 * k + 3], a1);
        b0 = dot2f(v.x, w1h[1][4 * k + 0], b0);
        b0 = dot2f(v.y, w1h[1][4 * k + 1], b0);
        b1 = dot2f(v.z, w1h[1][4 * k + 2], b1);
        b1 = dot2f(v.w, w1h[1][4 * k + 3], b1);
      }
      float accA = a0 + a1, accB = b0 + b1;
      accA = qp_add<0xB1>(accA); accA = qp_add<0x4E>(accA);
      accB = qp_add<0xB1>(accB); accB = qp_add<0x4E>(accB);
      float g0 = accA + bias[0];
      float g1 = accB + bias[1];
      float m = tp ? 2.0f : 1.0f;
      float act0 = m * sigm(m * g0) - (tp ? 1.0f : 0.0f);
      float act1 = sigm(g1);
      float e0 = swz_xor4(act0);
      float e1 = swz_xor4(act1);
      float ih = tp ? e0 : act0;
      float fh = tp ? e1 : act1;
      float gh = tp ? act0 : e0;
      float oh = tp ? act1 : e1;
      cst = fh * cst + ih * gh;
      float h = oh * tanh_f(cst);
      hlast = h;

      if ((tid & 7) == 0)
        ((_Float16*)hbuf)[(((t + 1) & 1) * 64) * 2 + c] = (_Float16)h;
      __syncthreads();
    }
    if ((tid & 7) == 0) out[b * HID + c] = hlast;
  }
}

extern "C" void kernel_launch(void* const* d_in, const int* in_sizes, int n_in,
                              void* d_out, int out_size, void* d_ws,
                              size_t ws_size, hipStream_t stream) {
  const float* x    = (const float*)d_in[0];
  const float* h0   = (const float*)d_in[1];
  const float* c0   = (const float*)d_in[2];
  const float* Wih0 = (const float*)d_in[3];
  const float* Whh0 = (const float*)d_in[4];
  const float* bih0 = (const float*)d_in[5];
  const float* bhh0 = (const float*)d_in[6];
  const float* Wih1 = (const float*)d_in[7];
  const float* Whh1 = (const float*)d_in[8];
  const float* bih1 = (const float*)d_in[9];
  const float* bhh1 = (const float*)d_in[10];

  lstm_fused<<<256, 1024, 0, stream>>>(x, h0, c0, Wih0, Whh0, bih0, bhh0,
                                       Wih1, Whh1, bih1, bhh1, (float*)d_out);
}

// Round 5
// 871.594 us; speedup vs baseline: 1.2913x; 1.2913x over previous
//
#include <hip/hip_runtime.h>

// OnsetLSTM: 2-layer LSTM, B=256, T=512, D=160, H=128, fp32 in/out.
// 256 blocks (1 batch row each) x 512 threads (8 waves, 2/SIMD).
// Thread = (cell c=tid>>2, K-chunk s=tid&3). Each thread holds ALL FOUR gate
// rows (i,f,g,o) of its cell over K/4 as 144 f16-pair VGPRs.
// amdgpu_waves_per_eu(2,2) pins the allocator budget at 256 VGPRs/thread so
// the weights stay register-resident (R2/R4 spilled at the default cap; the
// spill reloads made the kernel L2-BW-bound at ~1.2ms).
// Per step: 9 broadcast ds_read_b128 -> 144 v_dot2 -> 2-DPP quad butterfly
// per gate -> cell update replicated per quad -> 1 barrier. No gate LDS
// round-trip. Layer-0 h-sequence lives in LDS (128KB) and feeds layer 1.

typedef _Float16 half2_t __attribute__((ext_vector_type(2)));

#define TSTEPS 512
#define HID 128

static __device__ __forceinline__ unsigned pack2(float a, float b) {
  half2_t h; h[0] = (_Float16)a; h[1] = (_Float16)b;
  return __builtin_bit_cast(unsigned, h);
}

static __device__ __forceinline__ float dot2f(unsigned a, unsigned b, float c) {
#if __has_builtin(__builtin_amdgcn_fdot2)
  return __builtin_amdgcn_fdot2(__builtin_bit_cast(half2_t, a),
                                __builtin_bit_cast(half2_t, b), c, false);
#else
  half2_t x = __builtin_bit_cast(half2_t, a);
  half2_t y = __builtin_bit_cast(half2_t, b);
  float r = c;
  r = fmaf((float)x[0], (float)y[0], r);
  r = fmaf((float)x[1], (float)y[1], r);
  return r;
#endif
}

static __device__ __forceinline__ float fast_rcp(float x) {
#if __has_builtin(__builtin_amdgcn_rcpf)
  return __builtin_amdgcn_rcpf(x);
#else
  return 1.0f / x;
#endif
}
static __device__ __forceinline__ float fast_exp2(float x) {
#if __has_builtin(__builtin_amdgcn_exp2f)
  return __builtin_amdgcn_exp2f(x);
#else
  return exp2f(x);
#endif
}
// sigm(x) = 1/(1+2^(-x*log2e)); saturates correctly at +-inf
static __device__ __forceinline__ float sigm(float x) {
  return fast_rcp(1.0f + fast_exp2(x * -1.44269504f));
}
static __device__ __forceinline__ float tanh_f(float x) {
  // 1 - 2/(exp2(2x*log2e)+1); saturates correctly both ways
  float e = fast_exp2(x * 2.885390082f);
  return 1.0f - 2.0f * fast_rcp(e + 1.0f);
}

// butterfly add over quad (aligned groups of 4): CTRL 0xB1=xor1, 0x4E=xor2
template <int CTRL>
static __device__ __forceinline__ float qp_add(float v) {
  int iv = __builtin_bit_cast(int, v);
  int t = __builtin_amdgcn_update_dpp(iv, iv, CTRL, 0xF, 0xF, true);
  return v + __builtin_bit_cast(float, t);
}

__global__ __launch_bounds__(512) __attribute__((amdgpu_waves_per_eu(2, 2)))
void lstm_fused(
    const float* __restrict__ x,     // [256,512,160]
    const float* __restrict__ h0,    // [2,256,128]
    const float* __restrict__ c0,    // [2,256,128]
    const float* __restrict__ Wih0,  // [512,160]
    const float* __restrict__ Whh0,  // [512,128]
    const float* __restrict__ bih0, const float* __restrict__ bhh0,
    const float* __restrict__ Wih1,  // [512,128]
    const float* __restrict__ Whh1,  // [512,128]
    const float* __restrict__ bih1, const float* __restrict__ bhh1,
    float* __restrict__ out)         // [256,128]
{
  const int b   = blockIdx.x;
  const int tid = threadIdx.x;
  const int c   = tid >> 2;  // cell column 0..127
  const int s   = tid & 3;   // K-chunk 0..3

  __shared__ unsigned h1s[TSTEPS][64];  // 128 KB: layer-0 h_t as f16 pairs
  __shared__ unsigned xbuf[2][80];      // x_t as f16 pairs, double-buffered
  __shared__ unsigned h0buf[64];        // layer-0 initial h
  __shared__ unsigned hbuf[2][64];      // layer-1 recurrent h, double-buffered

  // ======================= Phase 0: layer 0 (K = 160 + 128) ==============
  {
    // rows r = g*128 + c for g in {i,f,g,o}; K-chunk s.
    // x-part: 80 pairs total -> 20/thread (5 uint4); h-part: 64 -> 16 (4 uint4).
    unsigned wx[4][20], wh[4][16];
    float bias[4];
#pragma unroll
    for (int g = 0; g < 4; ++g) {
      const int r = g * HID + c;
#pragma unroll
      for (int j = 0; j < 20; ++j) {
        int p = 20 * s + j;
        wx[g][j] = pack2(Wih0[r * 160 + 2 * p], Wih0[r * 160 + 2 * p + 1]);
      }
#pragma unroll
      for (int j = 0; j < 16; ++j) {
        int p = 16 * s + j;
        wh[g][j] = pack2(Whh0[r * HID + 2 * p], Whh0[r * HID + 2 * p + 1]);
      }
      bias[g] = bih0[r] + bhh0[r];
    }

    float cst = c0[b * HID + c];  // replicated across the quad

    if (tid < 64) h0buf[tid] = pack2(h0[b * HID + 2 * tid], h0[b * HID + 2 * tid + 1]);
    if (tid < 80) {
      float2 v = *(const float2*)&x[((size_t)b * TSTEPS + 0) * 160 + 2 * tid];
      xbuf[0][tid] = pack2(v.x, v.y);
    }
    float2 xA = make_float2(0.f, 0.f);  // x_{t+1} in regs
    if (tid < 80) xA = *(const float2*)&x[((size_t)b * TSTEPS + 1) * 160 + 2 * tid];
    __syncthreads();

#pragma unroll 1
    for (int t = 0; t < TSTEPS; ++t) {
      // issue x_{t+2} load now; consumed next iteration (latency hidden)
      float2 xB = xA;
      if (tid < 80) {
        int tn = (t + 2 < TSTEPS) ? t + 2 : TSTEPS - 1;
        xB = *(const float2*)&x[((size_t)b * TSTEPS + tn) * 160 + 2 * tid];
      }

      const uint4* xs = (const uint4*)&xbuf[t & 1][20 * s];
      const uint4* hs = (t == 0) ? (const uint4*)&h0buf[16 * s]
                                 : (const uint4*)&h1s[t - 1][16 * s];
      float ai = 0.f, af = 0.f, ag = 0.f, ao = 0.f;
#pragma unroll
      for (int k = 0; k < 5; ++k) {
        uint4 v = xs[k];
        ai = dot2f(v.x, wx[0][4 * k + 0], ai); ai = dot2f(v.y, wx[0][4 * k + 1], ai);
        ai = dot2f(v.z, wx[0][4 * k + 2], ai); ai = dot2f(v.w, wx[0][4 * k + 3], ai);
        af = dot2f(v.x, wx[1][4 * k + 0], af); af = dot2f(v.y, wx[1][4 * k + 1], af);
        af = dot2f(v.z, wx[1][4 * k + 2], af); af = dot2f(v.w, wx[1][4 * k + 3], af);
        ag = dot2f(v.x, wx[2][4 * k + 0], ag); ag = dot2f(v.y, wx[2][4 * k + 1], ag);
        ag = dot2f(v.z, wx[2][4 * k + 2], ag); ag = dot2f(v.w, wx[2][4 * k + 3], ag);
        ao = dot2f(v.x, wx[3][4 * k + 0], ao); ao = dot2f(v.y, wx[3][4 * k + 1], ao);
        ao = dot2f(v.z, wx[3][4 * k + 2], ao); ao = dot2f(v.w, wx[3][4 * k + 3], ao);
      }
#pragma unroll
      for (int k = 0; k < 4; ++k) {
        uint4 v = hs[k];
        ai = dot2f(v.x, wh[0][4 * k + 0], ai); ai = dot2f(v.y, wh[0][4 * k + 1], ai);
        ai = dot2f(v.z, wh[0][4 * k + 2], ai); ai = dot2f(v.w, wh[0][4 * k + 3], ai);
        af = dot2f(v.x, wh[1][4 * k + 0], af); af = dot2f(v.y, wh[1][4 * k + 1], af);
        af = dot2f(v.z, wh[1][4 * k + 2], af); af = dot2f(v.w, wh[1][4 * k + 3], af);
        ag = dot2f(v.x, wh[2][4 * k + 0], ag); ag = dot2f(v.y, wh[2][4 * k + 1], ag);
        ag = dot2f(v.z, wh[2][4 * k + 2], ag); ag = dot2f(v.w, wh[2][4 * k + 3], ag);
        ao = dot2f(v.x, wh[3][4 * k + 0], ao); ao = dot2f(v.y, wh[3][4 * k + 1], ao);
        ao = dot2f(v.z, wh[3][4 * k + 2], ao); ao = dot2f(v.w, wh[3][4 * k + 3], ao);
      }
      // quad butterfly: every lane of the quad gets all four full K-sums
      ai = qp_add<0xB1>(ai); ai = qp_add<0x4E>(ai);
      af = qp_add<0xB1>(af); af = qp_add<0x4E>(af);
      ag = qp_add<0xB1>(ag); ag = qp_add<0x4E>(ag);
      ao = qp_add<0xB1>(ao); ao = qp_add<0x4E>(ao);

      float iv = sigm(ai + bias[0]);
      float fv = sigm(af + bias[1]);
      float gv = tanh_f(ag + bias[2]);
      float ov = sigm(ao + bias[3]);
      cst = fv * cst + iv * gv;
      float h = ov * tanh_f(cst);

      if (s == 0) ((_Float16*)h1s)[t * HID + c] = (_Float16)h;
      if (tid < 80) xbuf[(t + 1) & 1][tid] = pack2(xA.x, xA.y);
      __syncthreads();
      xA = xB;
    }
  }

  // ======================= Phase 1: layer 1 (K = 128 + 128) ==============
  {
    unsigned w1x[4][16], w1h[4][16];
    float bias[4];
#pragma unroll
    for (int g = 0; g < 4; ++g) {
      const int r = g * HID + c;
#pragma unroll
      for (int j = 0; j < 16; ++j) {
        int p = 16 * s + j;
        w1x[g][j] = pack2(Wih1[r * HID + 2 * p], Wih1[r * HID + 2 * p + 1]);
        w1h[g][j] = pack2(Whh1[r * HID + 2 * p], Whh1[r * HID + 2 * p + 1]);
      }
      bias[g] = bih1[r] + bhh1[r];
    }

    const float* h0b = h0 + 256 * HID;
    const float* c0b = c0 + 256 * HID;
    float cst = c0b[b * HID + c];
    if (tid < 64) hbuf[0][tid] = pack2(h0b[b * HID + 2 * tid], h0b[b * HID + 2 * tid + 1]);
    __syncthreads();

    float hlast = 0.f;
#pragma unroll 1
    for (int t = 0; t < TSTEPS; ++t) {
      const uint4* xs = (const uint4*)&h1s[t][16 * s];       // layer-0 h_t
      const uint4* hs = (const uint4*)&hbuf[t & 1][16 * s];  // own h_{t-1}
      float ai = 0.f, af = 0.f, ag = 0.f, ao = 0.f;
#pragma unroll
      for (int k = 0; k < 4; ++k) {
        uint4 v = xs[k];
        ai = dot2f(v.x, w1x[0][4 * k + 0], ai); ai = dot2f(v.y, w1x[0][4 * k + 1], ai);
        ai = dot2f(v.z, w1x[0][4 * k + 2], ai); ai = dot2f(v.w, w1x[0][4 * k + 3], ai);
        af = dot2f(v.x, w1x[1][4 * k + 0], af); af = dot2f(v.y, w1x[1][4 * k + 1], af);
        af = dot2f(v.z, w1x[1][4 * k + 2], af); af = dot2f(v.w, w1x[1][4 * k + 3], af);
        ag = dot2f(v.x, w1x[2][4 * k + 0], ag); ag = dot2f(v.y, w1x[2][4 * k + 1], ag);
        ag = dot2f(v.z, w1x[2][4 * k + 2], ag); ag = dot2f(v.w, w1x[2][4 * k + 3], ag);
        ao = dot2f(v.x, w1x[3][4 * k + 0], ao); ao = dot2f(v.y, w1x[3][4 * k + 1], ao);
        ao = dot2f(v.z, w1x[3][4 * k + 2], ao); ao = dot2f(v.w, w1x[3][4 * k + 3], ao);
      }
#pragma unroll
      for (int k = 0; k < 4; ++k) {
        uint4 v = hs[k];
        ai = dot2f(v.x, w1h[0][4 * k + 0], ai); ai = dot2f(v.y, w1h[0][4 * k + 1], ai);
        ai = dot2f(v.z, w1h[0][4 * k + 2], ai); ai = dot2f(v.w, w1h[0][4 * k + 3], ai);
        af = dot2f(v.x, w1h[1][4 * k + 0], af); af = dot2f(v.y, w1h[1][4 * k + 1], af);
        af = dot2f(v.z, w1h[1][4 * k + 2], af); af = dot2f(v.w, w1h[1][4 * k + 3], af);
        ag = dot2f(v.x, w1h[2][4 * k + 0], ag); ag = dot2f(v.y, w1h[2][4 * k + 1], ag);
        ag = dot2f(v.z, w1h[2][4 * k + 2], ag); ag = dot2f(v.w, w1h[2][4 * k + 3], ag);
        ao = dot2f(v.x, w1h[3][4 * k + 0], ao); ao = dot2f(v.y, w1h[3][4 * k + 1], ao);
        ao = dot2f(v.z, w1h[3][4 * k + 2], ao); ao = dot2f(v.w, w1h[3][4 * k + 3], ao);
      }
      ai = qp_add<0xB1>(ai); ai = qp_add<0x4E>(ai);
      af = qp_add<0xB1>(af); af = qp_add<0x4E>(af);
      ag = qp_add<0xB1>(ag); ag = qp_add<0x4E>(ag);
      ao = qp_add<0xB1>(ao); ao = qp_add<0x4E>(ao);

      float iv = sigm(ai + bias[0]);
      float fv = sigm(af + bias[1]);
      float gv = tanh_f(ag + bias[2]);
      float ov = sigm(ao + bias[3]);
      cst = fv * cst + iv * gv;
      float h = ov * tanh_f(cst);
      hlast = h;

      if (s == 0) ((_Float16*)&hbuf[(t + 1) & 1][0])[c] = (_Float16)h;
      __syncthreads();
    }
    if (s == 0) out[b * HID + c] = hlast;
  }
}

extern "C" void kernel_launch(void* const* d_in, const int* in_sizes, int n_in,
                              void* d_out, int out_size, void* d_ws,
                              size_t ws_size, hipStream_t stream) {
  const float* x    = (const float*)d_in[0];
  const float* h0   = (const float*)d_in[1];
  const float* c0   = (const float*)d_in[2];
  const float* Wih0 = (const float*)d_in[3];
  const float* Whh0 = (const float*)d_in[4];
  const float* bih0 = (const float*)d_in[5];
  const float* bhh0 = (const float*)d_in[6];
  const float* Wih1 = (const float*)d_in[7];
  const float* Whh1 = (const float*)d_in[8];
  const float* bih1 = (const float*)d_in[9];
  const float* bhh1 = (const float*)d_in[10];

  lstm_fused<<<256, 512, 0, stream>>>(x, h0, c0, Wih0, Whh0, bih0, bhh0,
                                      Wih1, Whh1, bih1, bhh1, (float*)d_out);
}